// Round 8
// baseline (11435.904 us; speedup 1.0000x reference)
//
#include <hip/hip_runtime.h>

#define F1 1024
#define F4 4096
#define NB 16        // batch
#define NT 512       // time steps
#define NWG 256      // workgroups
#define NR (NT + 1)  // fused rounds 0..512
#define EPM (NR * NWG)

typedef float f32x4 __attribute__((ext_vector_type(4)));
typedef unsigned u32x4 __attribute__((ext_vector_type(4)));

// =====================================================================
// Kernel 1: Xi0 = x @ Wi0 + b0 (layer 0 only now), gate-col permuted:
//   col n = g*1024 + wg*4 + j  ->  wg*16 + g*4 + j
// =====================================================================
__global__ __launch_bounds__(256) void gemm_xi(
    const float* __restrict__ A, const float* __restrict__ Wi,
    const float* __restrict__ bias, float* __restrict__ Xi, int a_batch_major)
{
    __shared__ __align__(16) float As[16][68];
    __shared__ __align__(16) float Bs[16][68];
    const int tid = threadIdx.x;
    const int n0 = blockIdx.x * 64;
    const int m0 = blockIdx.y * 64;

    const int lrow = tid >> 2, lkq = tid & 3;
    const int bkr = tid >> 4, bnq = tid & 15;
    const int tm = tid & 15, tn = tid >> 4;

    const int m_l = m0 + lrow;
    const float* arow;
    if (a_batch_major) {
        int t = m_l >> 4, b = m_l & 15;
        arow = A + (size_t)(b * NT + t) * F1;
    } else {
        arow = A + (size_t)m_l * F1;
    }

    float acc[4][4];
#pragma unroll
    for (int i = 0; i < 4; i++)
#pragma unroll
        for (int j = 0; j < 4; j++) acc[i][j] = 0.f;

    for (int kc = 0; kc < F1; kc += 16) {
        float4 a4 = *(const float4*)(arow + kc + lkq * 4);
        float4 b4 = *(const float4*)(Wi + (size_t)(kc + bkr) * F4 + n0 + bnq * 4);
        __syncthreads();
        As[lkq * 4 + 0][lrow] = a4.x;
        As[lkq * 4 + 1][lrow] = a4.y;
        As[lkq * 4 + 2][lrow] = a4.z;
        As[lkq * 4 + 3][lrow] = a4.w;
        *(float4*)&Bs[bkr][bnq * 4] = b4;
        __syncthreads();
#pragma unroll
        for (int k = 0; k < 16; k++) {
            const float4 av = *(const float4*)&As[k][tm * 4];
            const float4 bv = *(const float4*)&Bs[k][tn * 4];
            float a_[4] = {av.x, av.y, av.z, av.w};
            float b_[4] = {bv.x, bv.y, bv.z, bv.w};
#pragma unroll
            for (int i = 0; i < 4; i++)
#pragma unroll
                for (int j = 0; j < 4; j++)
                    acc[i][j] = fmaf(a_[i], b_[j], acc[i][j]);
        }
    }

    const int n = n0 + tn * 4;
    const int g = n >> 10;
    const int wgi = (n & 1023) >> 2;
    const int np = wgi * 16 + g * 4;
    const float4 bi = *(const float4*)(bias + n);
#pragma unroll
    for (int i = 0; i < 4; i++) {
        int m = m0 + tm * 4 + i;
        float4 o;
        o.x = acc[i][0] + bi.x;
        o.y = acc[i][1] + bi.y;
        o.z = acc[i][2] + bi.z;
        o.w = acc[i][3] + bi.w;
        *(float4*)(Xi + (size_t)m * F4 + np) = o;
    }
}

// =====================================================================
// Kernel 2: FUSED two-layer LSTM, 1-step skew. Round r: L0 step r,
// L1 step r-1.  513 rounds instead of 2x512; L1's x-GEMM (h0@Wi1) is
// done in-kernel sharing the staged h0 tile (deletes gemm_xi layer 1).
// Thread (ks=tid>>2 in 0..127, cg=tid&3): 8-K slice x 4 gate-cols,
// all 16 rows. Weights (Wh0,Wi1,Wh1 slices) register-resident: 3x8
// f32x4/thread. 1-stage shfl_xor pre-reduce (ks-pairs) keeps the LDS
// partial buffer at 64 ks-levels (68KB).
// Sync: R7 dataflow scheme (per-producer epochs, 8 XCD mirrors).
// h exchange: fresh-address cached reads (R5 scheme): h0 via h0seq (ws),
// h1 via out[b][t][f] (written anyway).
// =====================================================================
__global__ __launch_bounds__(512, 2) void lstm_fused(
    const float* __restrict__ Wh0, const float* __restrict__ Wi1,
    const float* __restrict__ Wh1, const float* __restrict__ b1,
    const float* __restrict__ Xi0,   // [NT*NB][F4] permuted
    const float* __restrict__ c0in,  // [2][NB][F1]
    const float* __restrict__ h0in,  // [2][NB][F1]
    unsigned* __restrict__ ep,       // [8][NR][NWG] (memset 0)
    float* __restrict__ h0seq,       // [NT][NB][F1] (ws)
    float* __restrict__ out,         // [NB][NT][F1]
    float* __restrict__ cfin, float* __restrict__ hfin)
{
    const int tid = threadIdx.x;
    const int wg = blockIdx.x;
    const int ks = tid >> 2;   // 0..127 (K slice of 8)
    const int cg = tid & 3;    // gate (4 cols: wg*4..+3)

    __shared__ __align__(16) f32x4 hbuf4[16 * 257];  // h tile, swizzled (65.8KB)
    __shared__ __align__(16) f32x4 red4[256 * 17];   // partials [ks2*4+cg][16r] (69.6KB)
    __shared__ __align__(16) f32x4 red2[512];        // stage-1 sums (8KB)
    __shared__ float gbuf[16 * 20];                  // gates (1.3KB)

    // ---- weights -> registers: w[k] = 4 cols (gate cg) of K-row ks*8+k
    f32x4 wh0v[8], whxv[8], wh1v[8];
    {
        const size_t coff = (size_t)cg * F1 + wg * 4;
        const float* p0 = Wh0 + (size_t)(ks * 8) * F4 + coff;
        const float* px = Wi1 + (size_t)(ks * 8) * F4 + coff;
        const float* p1 = Wh1 + (size_t)(ks * 8) * F4 + coff;
#pragma unroll
        for (int k = 0; k < 8; ++k) {
            wh0v[k] = *(const f32x4*)(p0 + (size_t)k * F4);
            whxv[k] = *(const f32x4*)(px + (size_t)k * F4);
            wh1v[k] = *(const f32x4*)(p1 + (size_t)k * F4);
        }
    }

    // ---- per-thread act state (tid<64: row ab, h-col aj) + stage2 bias
    const int ab = tid >> 2, aj = tid & 3;
    float c0reg = 0.f, c1reg = 0.f;
    f32x4 b1v = {0.f, 0.f, 0.f, 0.f};
    if (tid < 64) {
        c0reg = c0in[ab * F1 + wg * 4 + aj];
        c1reg = c0in[NB * F1 + ab * F1 + wg * 4 + aj];
        b1v = *(const f32x4*)(b1 + (size_t)(tid & 3) * F1 + wg * 4);
    }

    for (int r = 0; r < NR; ++r) {
        // ---- P0: poll producers of round r-1 (wave 7, mirror wg&7)
        if (r > 0 && tid >= 448) {
            const unsigned target = (unsigned)r;
            const u32x4* fp = (const u32x4*)(ep + (size_t)(wg & 7) * EPM
                                               + (size_t)(r - 1) * NWG) + (tid - 448);
            while (true) {
                u32x4 fv;
                asm volatile("global_load_dwordx4 %0, %1, off sc1"
                             : "=v"(fv) : "v"(fp));
                asm volatile("s_waitcnt vmcnt(0)" ::: "memory");
                int ok = (fv.x >= target) & (fv.y >= target) &
                         (fv.z >= target) & (fv.w >= target);
                if (__all(ok)) break;
            }
        }
        __syncthreads();  // S1

        // ---- P1: gather h0(r-1) -> hbuf; ISSUE h1(r-2) loads (held in
        // regs to P5); prefetch Xi0 row (act/stage2 threads)
        f32x4 vv2[8];
        f32x4 xi0v = {0.f, 0.f, 0.f, 0.f};
        {
            const float* hs0 = (r == 0) ? h0in
                                        : (h0seq + (size_t)(r - 1) * (NB * F1));
            f32x4 vv[8];
#pragma unroll
            for (int c = 0; c < 8; ++c)
                vv[c] = *((const f32x4*)hs0 + c * 512 + tid);
            if (r >= 1) {
                if (r == 1) {
                    const f32x4* hs1 = (const f32x4*)(h0in + NB * F1);
#pragma unroll
                    for (int c = 0; c < 8; ++c) vv2[c] = hs1[c * 512 + tid];
                } else {
                    const float* hs1 = out + (size_t)(r - 2) * F1;
#pragma unroll
                    for (int c = 0; c < 8; ++c) {
                        int f4 = c * 512 + tid;
                        vv2[c] = *(const f32x4*)(hs1
                                   + (size_t)(f4 >> 8) * ((size_t)NT * F1)
                                   + (size_t)(f4 & 255) * 4);
                    }
                }
            }
            if (tid < 64) {
                int tX = (r < NT) ? r : NT - 1;
                xi0v = *(const f32x4*)(Xi0 + (size_t)(tX * NB + ab) * F4
                                           + wg * 16 + (tid & 3) * 4);
            }
#pragma unroll
            for (int c = 0; c < 8; ++c) {
                int f4 = c * 512 + tid;
                int rr = f4 >> 8, k4 = f4 & 255;
                hbuf4[rr * 257 + (k4 ^ ((k4 >> 3) & 7))] = vv[c];
            }
        }
        __syncthreads();  // S2

        // ---- P2: GEMM-A1 (L0h: h0 x Wh0) -> acc; pair-butterfly; write red
        f32x4 acc[16];
#pragma unroll
        for (int i = 0; i < 16; ++i) acc[i] = (f32x4){0.f, 0.f, 0.f, 0.f};
#pragma unroll
        for (int k4l = 0; k4l < 2; ++k4l) {
            const int k4 = (ks << 1) + k4l;
            const int slot = k4 ^ ((k4 >> 3) & 7);
#pragma unroll
            for (int rr = 0; rr < 16; ++rr) {
                f32x4 hv = hbuf4[rr * 257 + slot];
                acc[rr] += hv.x * wh0v[k4l * 4 + 0];
                acc[rr] += hv.y * wh0v[k4l * 4 + 1];
                acc[rr] += hv.z * wh0v[k4l * 4 + 2];
                acc[rr] += hv.w * wh0v[k4l * 4 + 3];
            }
        }
#pragma unroll
        for (int rr = 0; rr < 16; ++rr) {
            f32x4 o;
            o.x = __shfl_xor(acc[rr].x, 4);
            o.y = __shfl_xor(acc[rr].y, 4);
            o.z = __shfl_xor(acc[rr].z, 4);
            o.w = __shfl_xor(acc[rr].w, 4);
            acc[rr] += o;
        }
        if ((ks & 1) == 0) {
            const int base = ((ks >> 1) * 4 + cg) * 17;
#pragma unroll
            for (int rr = 0; rr < 16; ++rr) red4[base + rr] = acc[rr];
        }
        __syncthreads();  // S3

        // ---- P3: stage1 reduce L0 (512 thr: (rw,cgq,kq) sums 8 ks2)
        {
            const int rw = tid >> 5, cgq = (tid >> 3) & 3, kq = tid & 7;
            f32x4 s = {0.f, 0.f, 0.f, 0.f};
#pragma unroll
            for (int j = 0; j < 8; ++j)
                s += red4[((kq * 8 + j) * 4 + cgq) * 17 + rw];
            red2[(rw * 4 + cgq) * 8 + kq] = s;
        }
        __syncthreads();  // S4

        // ---- P4: stage2-L0 -> gbuf (+Xi0, has b0); all: GEMM-A2 (L1x)
        if (tid < 64) {
            f32x4 s = xi0v;
#pragma unroll
            for (int kq = 0; kq < 8; ++kq) s += red2[tid * 8 + kq];
            *(f32x4*)&gbuf[(tid >> 2) * 20 + (tid & 3) * 4] = s;
        }
#pragma unroll
        for (int i = 0; i < 16; ++i) acc[i] = (f32x4){0.f, 0.f, 0.f, 0.f};
        if (r >= 1) {
#pragma unroll
            for (int k4l = 0; k4l < 2; ++k4l) {
                const int k4 = (ks << 1) + k4l;
                const int slot = k4 ^ ((k4 >> 3) & 7);
#pragma unroll
                for (int rr = 0; rr < 16; ++rr) {
                    f32x4 hv = hbuf4[rr * 257 + slot];
                    acc[rr] += hv.x * whxv[k4l * 4 + 0];
                    acc[rr] += hv.y * whxv[k4l * 4 + 1];
                    acc[rr] += hv.z * whxv[k4l * 4 + 2];
                    acc[rr] += hv.w * whxv[k4l * 4 + 3];
                }
            }
        }
        __syncthreads();  // S5

        // ---- P5: swap hbuf -> h1(r-2); act0 (L0 step r)
        if (r >= 1) {
#pragma unroll
            for (int c = 0; c < 8; ++c) {
                int f4 = c * 512 + tid;
                int rr = f4 >> 8, k4 = f4 & 255;
                hbuf4[rr * 257 + (k4 ^ ((k4 >> 3) & 7))] = vv2[c];
            }
        }
        if (tid < 64 && r < NT) {
            float gi = gbuf[ab * 20 + 0 + aj];
            float gf = gbuf[ab * 20 + 4 + aj];
            float gg = gbuf[ab * 20 + 8 + aj];
            float go = gbuf[ab * 20 + 12 + aj];
            float si = 1.f / (1.f + __expf(-gi));
            float sf = 1.f / (1.f + __expf(-gf));
            float so = 1.f / (1.f + __expf(-go));
            float tg = 1.f - 2.f / (__expf(2.f * gg) + 1.f);
            float cn = sf * c0reg + si * tg;
            float tc = 1.f - 2.f / (__expf(2.f * cn) + 1.f);
            float hn = so * tc;
            c0reg = cn;
            float* hp = h0seq + (size_t)r * (NB * F1) + ab * F1 + wg * 4 + aj;
            __hip_atomic_store(hp, hn, __ATOMIC_RELAXED, __HIP_MEMORY_SCOPE_AGENT);
            if (r == NT - 1) {
                cfin[ab * F1 + wg * 4 + aj] = cn;
                hfin[ab * F1 + wg * 4 + aj] = hn;
            }
        }
        __syncthreads();  // S6

        // ---- P6: GEMM-B (L1h: h1 x Wh1) accumulate; butterfly; write red
        if (r >= 1) {
#pragma unroll
            for (int k4l = 0; k4l < 2; ++k4l) {
                const int k4 = (ks << 1) + k4l;
                const int slot = k4 ^ ((k4 >> 3) & 7);
#pragma unroll
                for (int rr = 0; rr < 16; ++rr) {
                    f32x4 hv = hbuf4[rr * 257 + slot];
                    acc[rr] += hv.x * wh1v[k4l * 4 + 0];
                    acc[rr] += hv.y * wh1v[k4l * 4 + 1];
                    acc[rr] += hv.z * wh1v[k4l * 4 + 2];
                    acc[rr] += hv.w * wh1v[k4l * 4 + 3];
                }
            }
#pragma unroll
            for (int rr = 0; rr < 16; ++rr) {
                f32x4 o;
                o.x = __shfl_xor(acc[rr].x, 4);
                o.y = __shfl_xor(acc[rr].y, 4);
                o.z = __shfl_xor(acc[rr].z, 4);
                o.w = __shfl_xor(acc[rr].w, 4);
                acc[rr] += o;
            }
            if ((ks & 1) == 0) {
                const int base = ((ks >> 1) * 4 + cg) * 17;
#pragma unroll
                for (int rr = 0; rr < 16; ++rr) red4[base + rr] = acc[rr];
            }
        }
        __syncthreads();  // S7

        // ---- P7: stage1 reduce L1
        if (r >= 1) {
            const int rw = tid >> 5, cgq = (tid >> 3) & 3, kq = tid & 7;
            f32x4 s = {0.f, 0.f, 0.f, 0.f};
#pragma unroll
            for (int j = 0; j < 8; ++j)
                s += red4[((kq * 8 + j) * 4 + cgq) * 17 + rw];
            red2[(rw * 4 + cgq) * 8 + kq] = s;
        }
        __syncthreads();  // S8

        // ---- P8: stage2-L1 -> gbuf (+b1)
        if (r >= 1 && tid < 64) {
            f32x4 s = b1v;
#pragma unroll
            for (int kq = 0; kq < 8; ++kq) s += red2[tid * 8 + kq];
            *(f32x4*)&gbuf[(tid >> 2) * 20 + (tid & 3) * 4] = s;
        }
        __syncthreads();  // S9

        // ---- P9: act1 (L1 step r-1); drain; publish epoch r+1
        if (tid < 64) {
            if (r >= 1) {
                float gi = gbuf[ab * 20 + 0 + aj];
                float gf = gbuf[ab * 20 + 4 + aj];
                float gg = gbuf[ab * 20 + 8 + aj];
                float go = gbuf[ab * 20 + 12 + aj];
                float si = 1.f / (1.f + __expf(-gi));
                float sf = 1.f / (1.f + __expf(-gf));
                float so = 1.f / (1.f + __expf(-go));
                float tg = 1.f - 2.f / (__expf(2.f * gg) + 1.f);
                float cn = sf * c1reg + si * tg;
                float tc = 1.f - 2.f / (__expf(2.f * cn) + 1.f);
                float hn = so * tc;
                c1reg = cn;
                float* hp = out + (size_t)ab * ((size_t)NT * F1)
                                + (size_t)(r - 1) * F1 + wg * 4 + aj;
                __hip_atomic_store(hp, hn, __ATOMIC_RELAXED, __HIP_MEMORY_SCOPE_AGENT);
                if (r == NT) {
                    cfin[NB * F1 + ab * F1 + wg * 4 + aj] = cn;
                    hfin[NB * F1 + ab * F1 + wg * 4 + aj] = hn;
                }
            }
            // drain h0(r) + h1(r-1) stores to coherent point, then publish
            asm volatile("s_waitcnt vmcnt(0)" ::: "memory");
            if (tid < 8)
                __hip_atomic_store(ep + (size_t)tid * EPM + (size_t)r * NWG + wg,
                                   (unsigned)(r + 1), __ATOMIC_RELAXED,
                                   __HIP_MEMORY_SCOPE_AGENT);
        }
        // next round's S1 closes the loop
    }
}

// =====================================================================
// Launch
// =====================================================================
extern "C" void kernel_launch(void* const* d_in, const int* in_sizes, int n_in,
                              void* d_out, int out_size, void* d_ws, size_t ws_size,
                              hipStream_t stream) {
    const float* x = (const float*)d_in[0];     // [16][512][1024]
    const float* Wi = (const float*)d_in[1];    // [2][1024][4096]
    const float* Wh = (const float*)d_in[2];    // [2][1024][4096]
    const float* bias = (const float*)d_in[3];  // [2][4096]
    const float* c0 = (const float*)d_in[4];    // [2][16][1024]
    const float* h0 = (const float*)d_in[5];    // [2][16][1024]
    float* out = (float*)d_out;

    float* Xi0 = (float*)d_ws;                               // 134.2MB
    float* h0seq = Xi0 + (size_t)NT * NB * F4;               // [NT][16][1024] 33.6MB
    unsigned* ep = (unsigned*)(h0seq + (size_t)NT * NB * F1); // [8][NR][NWG] 4.2MB

    float* cfin = out + (size_t)NB * NT * F1;
    float* hfin = cfin + 2 * NB * F1;

    const size_t lw = (size_t)F1 * F4;

    hipMemsetAsync(ep, 0, (size_t)8 * EPM * sizeof(unsigned), stream);

    // layer-0 input GEMM (layer 1's is fused into the recurrence)
    gemm_xi<<<dim3(64, 128), dim3(256), 0, stream>>>(x, Wi, bias, Xi0, 1);

    {
        const float* a0 = Wh;              // Wh0
        const float* a1 = Wi + lw;         // Wi1
        const float* a2 = Wh + lw;         // Wh1
        const float* a3 = bias + F4;       // b1
        const float* a4 = Xi0;
        const float* a5 = c0;
        const float* a6 = h0;
        unsigned* a7 = ep;
        float* a8 = h0seq;
        float* a9 = out;
        float* a10 = cfin;
        float* a11 = hfin;
        void* args[] = {&a0, &a1, &a2, &a3, &a4, &a5, &a6, &a7, &a8, &a9, &a10, &a11};
        hipLaunchCooperativeKernel((void*)lstm_fused, dim3(NWG), dim3(512), args, 0, stream);
    }
}